// Round 6
// baseline (1236.284 us; speedup 1.0000x reference)
//
#include <hip/hip_runtime.h>
#include <math.h>

#define NF        128
#define H_DIM     256
#define NA        200
#define B_SAMPLES 512
#define ALPHA_LR  0.01f
#define B_MIN_C   1e-4f

#define NTHREADS  512
#define ROWS_PER_WAVE 25            // exact-path: 8 waves x 25 rows
#define SLAB_STRIDE 27              // odd -> 2-way bank aliasing (free)

#define N_PH1     10
#define N_REFINE  2
#define CG_MAX    40
#define TOL2_LO   4e-4f
#define TOL2_HI   2.5e-2f

// ---------------- DPP wave-64 reductions (result valid in lane 63) --------
__device__ __forceinline__ float dpp_wave_sum(float v){
  v += __int_as_float(__builtin_amdgcn_update_dpp(0, __float_as_int(v), 0x111, 0xf, 0xf, false));
  v += __int_as_float(__builtin_amdgcn_update_dpp(0, __float_as_int(v), 0x112, 0xf, 0xf, false));
  v += __int_as_float(__builtin_amdgcn_update_dpp(0, __float_as_int(v), 0x114, 0xf, 0xf, false));
  v += __int_as_float(__builtin_amdgcn_update_dpp(0, __float_as_int(v), 0x118, 0xf, 0xf, false));
  v += __int_as_float(__builtin_amdgcn_update_dpp(0, __float_as_int(v), 0x142, 0xa, 0xf, false));
  v += __int_as_float(__builtin_amdgcn_update_dpp(0, __float_as_int(v), 0x143, 0xc, 0xf, false));
  return v;
}
__device__ __forceinline__ float dpp_wave_min(float v){
  const int PINF = 0x7f800000;
  v = fminf(v, __int_as_float(__builtin_amdgcn_update_dpp(PINF, __float_as_int(v), 0x111, 0xf, 0xf, false)));
  v = fminf(v, __int_as_float(__builtin_amdgcn_update_dpp(PINF, __float_as_int(v), 0x112, 0xf, 0xf, false)));
  v = fminf(v, __int_as_float(__builtin_amdgcn_update_dpp(PINF, __float_as_int(v), 0x114, 0xf, 0xf, false)));
  v = fminf(v, __int_as_float(__builtin_amdgcn_update_dpp(PINF, __float_as_int(v), 0x118, 0xf, 0xf, false)));
  v = fminf(v, __int_as_float(__builtin_amdgcn_update_dpp(PINF, __float_as_int(v), 0x142, 0xa, 0xf, false)));
  v = fminf(v, __int_as_float(__builtin_amdgcn_update_dpp(PINF, __float_as_int(v), 0x143, 0xc, 0xf, false)));
  return v;
}
__device__ __forceinline__ float dpp_wave_max(float v){
  const int NINF = 0xff800000;
  v = fmaxf(v, __int_as_float(__builtin_amdgcn_update_dpp(NINF, __float_as_int(v), 0x111, 0xf, 0xf, false)));
  v = fmaxf(v, __int_as_float(__builtin_amdgcn_update_dpp(NINF, __float_as_int(v), 0x112, 0xf, 0xf, false)));
  v = fmaxf(v, __int_as_float(__builtin_amdgcn_update_dpp(NINF, __float_as_int(v), 0x114, 0xf, 0xf, false)));
  v = fmaxf(v, __int_as_float(__builtin_amdgcn_update_dpp(NINF, __float_as_int(v), 0x118, 0xf, 0xf, false)));
  v = fmaxf(v, __int_as_float(__builtin_amdgcn_update_dpp(NINF, __float_as_int(v), 0x142, 0xa, 0xf, false)));
  v = fmaxf(v, __int_as_float(__builtin_amdgcn_update_dpp(NINF, __float_as_int(v), 0x143, 0xc, 0xf, false)));
  return v;
}
// block reductions (prologue only)
__device__ __forceinline__ float block_sum8(float v, float* red8, int tid){
  __syncthreads();
  v = dpp_wave_sum(v);
  if ((tid & 63) == 63) red8[tid >> 6] = v;
  __syncthreads();
  float o = red8[0];
  #pragma unroll
  for (int w = 1; w < 8; ++w) o += red8[w];
  return o;
}
__device__ __forceinline__ float block_max8(float v, float* red8, int tid){
  __syncthreads();
  v = dpp_wave_max(v);
  if ((tid & 63) == 63) red8[tid >> 6] = v;
  __syncthreads();
  float o = red8[0];
  #pragma unroll
  for (int w = 1; w < 8; ++w) o = fmaxf(o, red8[w]);
  return o;
}

__device__ __forceinline__ unsigned pack_bf16(float a, float b){
  unsigned bx = __float_as_uint(a); bx = (bx + 0x7fffu + ((bx >> 16) & 1u)) >> 16;
  unsigned by = __float_as_uint(b); by = (by + 0x7fffu + ((by >> 16) & 1u)) >> 16;
  return bx | (by << 16);
}

// hybrid half-row matvec: 25 packed dwords from VGPRs + 25 from LDS slab
__device__ __forceinline__ float mv_hybrid(const unsigned* mreg,
                                           const unsigned* __restrict__ slab,
                                           const float* __restrict__ vv,
                                           int tid, int half){
  const float2* v2 = (const float2*)vv + half * 50;
  const unsigned* sl = slab + tid * SLAB_STRIDE;
  float a0=0.f, a1=0.f, a2=0.f, a3=0.f;
  #pragma unroll
  for (int k = 0; k < 25; ++k){
    unsigned u = mreg[k]; float2 x = v2[k];
    a0 = fmaf(__uint_as_float(u << 16),          x.x, a0);
    a1 = fmaf(__uint_as_float(u & 0xffff0000u),  x.y, a1);
  }
  #pragma unroll
  for (int k = 0; k < 25; ++k){
    unsigned u = sl[k]; float2 x = v2[25 + k];
    a2 = fmaf(__uint_as_float(u << 16),          x.x, a2);
    a3 = fmaf(__uint_as_float(u & 0xffff0000u),  x.y, a3);
  }
  return (a0 + a1) + (a2 + a3);
}

extern "C" __global__ __launch_bounds__(NTHREADS, 4)
void rb_kernel(const float* __restrict__ x,  const float* __restrict__ Sigma,
               const float* __restrict__ W1, const float* __restrict__ b1,
               const float* __restrict__ W2, const float* __restrict__ b2,
               float* __restrict__ out) {
  __shared__ __align__(16) unsigned slab[400 * SLAB_STRIDE];   // 43.2 KB
  __shared__ __align__(16) float yv[NA];
  __shared__ __align__(16) float pv[NA];
  __shared__ __align__(16) float partial[NA];
  __shared__ __align__(16) float bcv[NA];
  __shared__ float xs[NF];
  __shared__ float hs[H_DIM];
  __shared__ float redA[8], redB[8], redC[8], redD[8], red8[8];

  const int tid  = threadIdx.x;
  const int s    = blockIdx.x;
  const bool act = tid < 400;
  const int row  = tid >> 1;              // valid when act
  const int half = tid & 1;
  const bool owner = act && (half == 0);
  const float* S = Sigma + (size_t)s * NA * NA;

  if (tid < NF) xs[tid] = x[s * NF + tid];
  float sd = 0.f;
  if (owner) sd = S[(size_t)row * NA + row];

  // ---- stage Sigma directly: 25 packed dwords -> VGPRs, 25 -> private slab row ----
  // Only the owning thread ever reads its slab row -> no staging barriers.
  unsigned mreg[25];
  if (act){
    const float2* rowp = (const float2*)S + (size_t)row * 100 + half * 50;
    #pragma unroll
    for (int k = 0; k < 25; ++k){
      float2 w = rowp[k];
      mreg[k] = pack_bf16(w.x, w.y);
    }
    unsigned* sl = slab + tid * SLAB_STRIDE;
    #pragma unroll
    for (int k = 0; k < 25; ++k){
      float2 w = rowp[25 + k];
      sl[k] = pack_bf16(w.x, w.y);
    }
  }

  // ---- MLP ----
  __syncthreads();                        // xs visible
  if (tid < H_DIM){
    const float* w = W1 + tid * NF;
    float acc = b1[tid];
    #pragma unroll 8
    for (int j = 0; j < NF; ++j) acc += w[j] * xs[j];
    hs[tid] = (acc >= 0.f) ? acc : ALPHA_LR * acc;
  }
  __syncthreads();
  float logit = -INFINITY;
  if (tid < NA){
    const float* w = W2 + tid * H_DIM;
    float acc = b2[tid];
    #pragma unroll 8
    for (int j = 0; j < H_DIM; ++j) acc += w[j] * hs[j];
    logit = acc;
  }

  // ---- softmax -> b (output 2); clamp+renorm -> bcv ----
  float mx = block_max8(logit, red8, tid);
  float e  = (tid < NA) ? expf(logit - mx) : 0.f;
  float es = block_sum8(e, red8, tid);
  float bsoft = e / es;
  if (tid < NA) out[(size_t)B_SAMPLES * NA + (size_t)s * NA + tid] = bsoft;
  float bcl = fmaxf(bsoft, B_MIN_C);
  float bs  = block_sum8((tid < NA) ? bcl : 0.f, red8, tid);
  if (tid < NA) bcv[tid] = bcl / bs;
  __syncthreads();                               // bcv visible

  float b_ = owner ? bcv[row] : 0.f;
  float y  = 0.f;
  if (owner) yv[row] = b_;

  // ---- y0 = bc / sqrt(bc^T S bc) ----
  __syncthreads();                               // yv visible
  {
    float acc = act ? mv_hybrid(mreg, slab, yv, tid, half) : 0.f;
    float q   = acc + __shfl_xor(acc, 1, 64);
    float wq  = dpp_wave_sum(owner ? b_ * q : 0.f);
    if ((tid & 63) == 63) redA[tid >> 6] = wq;
    __syncthreads();
    float quad = redA[0]+redA[1]+redA[2]+redA[3]+redA[4]+redA[5]+redA[6]+redA[7];
    if (owner){ y = b_ / sqrtf(quad); yv[row] = y; }
  }

  // ---- damped inexact Newton ----
  float gg0 = 1.f;
  bool  ph1done = false;
  int   nexact  = 0;
  for (int it = 0; it < N_PH1 + N_REFINE; ++it){
    if (nexact >= N_REFINE) break;
    const bool exact = ph1done;
    if (exact) ++nexact;

    // --- gradient matvec q = (S y)_row ---
    float q = 0.f;
    if (exact){
      __syncthreads();                           // yv visible, partial free
      int lane = tid & 63, wid = tid >> 6;
      int r0 = wid * ROWS_PER_WAVE;
      for (int rr = r0; rr < r0 + ROWS_PER_WAVE; ++rr){
        const float* rowp = S + (size_t)rr * NA;
        float a = rowp[lane]*yv[lane] + rowp[lane+64]*yv[lane+64]
                + rowp[lane+128]*yv[lane+128];
        if (lane < NA - 192) a += rowp[lane+192]*yv[lane+192];
        a = dpp_wave_sum(a);
        if (lane == 63) partial[rr] = a;
      }
      __syncthreads();
      if (owner) q = partial[row];
    } else {
      __syncthreads();                           // yv visible
      float acc = act ? mv_hybrid(mreg, slab, yv, tid, half) : 0.f;
      q = acc + __shfl_xor(acc, 1, 64);
    }

    // --- Newton init ---
    float g=0.f, d=0.f, mi=0.f, r=0.f, z=0.f, dy=0.f, pj=0.f;
    if (owner){
      g  = q - b_ / y;
      d  = b_ / (y * y);
      mi = 1.f / (sd + d);
      r  = -g; z = mi * r; pj = z;
      pv[row] = z;
    }
    float wg = dpp_wave_sum(owner ? g * g : 0.f);
    float wz = dpp_wave_sum(owner ? r * z : 0.f);
    if ((tid & 63) == 63){ redA[tid >> 6] = wg; redB[tid >> 6] = wz; }
    __syncthreads();
    float gg = redA[0]+redA[1]+redA[2]+redA[3]+redA[4]+redA[5]+redA[6]+redA[7];
    float rz = redB[0]+redB[1]+redB[2]+redB[3]+redB[4]+redB[5]+redB[6]+redB[7];
    if (it == 0) gg0 = fmaxf(gg, 1e-30f);
    float tol2 = exact ? TOL2_LO
                       : fminf(TOL2_HI, fmaxf(TOL2_LO, 4.f * (gg / gg0)));

    if (gg > 1e-24f){
      // --- Jacobi-PCG, fused single reduction (pq, rq, qq) ---
      const float rz0 = rz;
      for (int j = 0; j < CG_MAX; ++j){
        __syncthreads();                         // B1: pv visible, red reuse safe
        float acc = act ? mv_hybrid(mreg, slab, pv, tid, half) : 0.f;
        float qp  = acc + __shfl_xor(acc, 1, 64);
        float qf=0.f, cpq=0.f, crq=0.f, cqq=0.f;
        if (owner){
          qf = qp + d * pj;
          float u = mi * qf;
          cpq = pj * qf; crq = r * u; cqq = qf * u;
        }
        cpq = dpp_wave_sum(cpq); crq = dpp_wave_sum(crq); cqq = dpp_wave_sum(cqq);
        if ((tid & 63) == 63){ redA[tid>>6]=cpq; redB[tid>>6]=crq; redC[tid>>6]=cqq; }
        __syncthreads();                         // B2
        float pq = redA[0]+redA[1]+redA[2]+redA[3]+redA[4]+redA[5]+redA[6]+redA[7];
        float rq = redB[0]+redB[1]+redB[2]+redB[3]+redB[4]+redB[5]+redB[6]+redB[7];
        float qq = redC[0]+redC[1]+redC[2]+redC[3]+redC[4]+redC[5]+redC[6]+redC[7];
        float alpha = rz / pq;
        float rznew = fmaxf(fmaf(alpha*alpha, qq, fmaf(-2.f*alpha, rq, rz)), 0.f);
        if (owner){
          dy = fmaf(alpha, pj, dy);
          r  = fmaf(-alpha, qf, r);
          z  = mi * r;
        }
        bool brk = (rznew <= tol2 * rz0) || (j == CG_MAX - 1);
        if (!brk){
          float beta = rznew / rz;
          if (owner){ pj = fmaf(beta, pj, z); pv[row] = pj; }
        }
        rz = rznew;
        if (brk) break;
      }

      // --- damped step keeping y > 0 (reference semantics) ---
      float ratio = (owner && dy < 0.f) ? (-y / dy) : 1e30f;
      float wmn = dpp_wave_min(ratio);
      if ((tid & 63) == 63) redD[tid >> 6] = wmn;
      __syncthreads();
      float mr = fminf(fminf(fminf(redD[0],redD[1]),fminf(redD[2],redD[3])),
                       fminf(fminf(redD[4],redD[5]),fminf(redD[6],redD[7])));
      float t = fminf(1.f, 0.9f * mr);
      if (owner){ y = fmaxf(fmaf(t, dy, y), 1e-12f); yv[row] = y; }
    }

    if (!exact && (gg <= 1e-8f * gg0 || it + 1 >= N_PH1)) ph1done = true;
  }

  // ---- z = y / sum(y) (output 1) ----
  float wy = dpp_wave_sum(owner ? y : 0.f);
  if ((tid & 63) == 63) redA[tid >> 6] = wy;   // safe: barrier passed since last redA read
  __syncthreads();
  float ys = redA[0]+redA[1]+redA[2]+redA[3]+redA[4]+redA[5]+redA[6]+redA[7];
  if (owner) out[(size_t)s * NA + row] = y / ys;
}

extern "C" void kernel_launch(void* const* d_in, const int* in_sizes, int n_in,
                              void* d_out, int out_size, void* d_ws, size_t ws_size,
                              hipStream_t stream) {
  const float* x     = (const float*)d_in[0];
  const float* Sigma = (const float*)d_in[1];
  const float* W1    = (const float*)d_in[2];
  const float* b1    = (const float*)d_in[3];
  const float* W2    = (const float*)d_in[4];
  const float* b2    = (const float*)d_in[5];
  float* out = (float*)d_out;
  hipLaunchKernelGGL(rb_kernel, dim3(B_SAMPLES), dim3(NTHREADS), 0, stream,
                     x, Sigma, W1, b1, W2, b2, out);
}

// Round 7
// 518.166 us; speedup vs baseline: 2.3859x; 2.3859x over previous
//
#include <hip/hip_runtime.h>
#include <math.h>

#define NF        128
#define H_DIM     256
#define NA        200
#define B_SAMPLES 512
#define ALPHA_LR  0.01f
#define B_MIN_C   1e-4f

#define NTHREADS  512
#define ROWS_PER_WAVE 25            // exact-path: 8 waves x 25 rows
#define SLAB_STRIDE 27              // odd -> 2-way bank aliasing (free)

#define N_PH1     10
#define N_REFINE  2
#define CG_MAX    40
#define TOL2_LO   4e-4f
#define TOL2_HI   2.5e-2f

// ---------------- DPP wave-64 reductions (result valid in lane 63) --------
__device__ __forceinline__ float dpp_wave_sum(float v){
  v += __int_as_float(__builtin_amdgcn_update_dpp(0, __float_as_int(v), 0x111, 0xf, 0xf, false));
  v += __int_as_float(__builtin_amdgcn_update_dpp(0, __float_as_int(v), 0x112, 0xf, 0xf, false));
  v += __int_as_float(__builtin_amdgcn_update_dpp(0, __float_as_int(v), 0x114, 0xf, 0xf, false));
  v += __int_as_float(__builtin_amdgcn_update_dpp(0, __float_as_int(v), 0x118, 0xf, 0xf, false));
  v += __int_as_float(__builtin_amdgcn_update_dpp(0, __float_as_int(v), 0x142, 0xa, 0xf, false));
  v += __int_as_float(__builtin_amdgcn_update_dpp(0, __float_as_int(v), 0x143, 0xc, 0xf, false));
  return v;
}
__device__ __forceinline__ float dpp_wave_min(float v){
  const int PINF = 0x7f800000;
  v = fminf(v, __int_as_float(__builtin_amdgcn_update_dpp(PINF, __float_as_int(v), 0x111, 0xf, 0xf, false)));
  v = fminf(v, __int_as_float(__builtin_amdgcn_update_dpp(PINF, __float_as_int(v), 0x112, 0xf, 0xf, false)));
  v = fminf(v, __int_as_float(__builtin_amdgcn_update_dpp(PINF, __float_as_int(v), 0x114, 0xf, 0xf, false)));
  v = fminf(v, __int_as_float(__builtin_amdgcn_update_dpp(PINF, __float_as_int(v), 0x118, 0xf, 0xf, false)));
  v = fminf(v, __int_as_float(__builtin_amdgcn_update_dpp(PINF, __float_as_int(v), 0x142, 0xa, 0xf, false)));
  v = fminf(v, __int_as_float(__builtin_amdgcn_update_dpp(PINF, __float_as_int(v), 0x143, 0xc, 0xf, false)));
  return v;
}
__device__ __forceinline__ float dpp_wave_max(float v){
  const int NINF = 0xff800000;
  v = fmaxf(v, __int_as_float(__builtin_amdgcn_update_dpp(NINF, __float_as_int(v), 0x111, 0xf, 0xf, false)));
  v = fmaxf(v, __int_as_float(__builtin_amdgcn_update_dpp(NINF, __float_as_int(v), 0x112, 0xf, 0xf, false)));
  v = fmaxf(v, __int_as_float(__builtin_amdgcn_update_dpp(NINF, __float_as_int(v), 0x114, 0xf, 0xf, false)));
  v = fmaxf(v, __int_as_float(__builtin_amdgcn_update_dpp(NINF, __float_as_int(v), 0x118, 0xf, 0xf, false)));
  v = fmaxf(v, __int_as_float(__builtin_amdgcn_update_dpp(NINF, __float_as_int(v), 0x142, 0xa, 0xf, false)));
  v = fmaxf(v, __int_as_float(__builtin_amdgcn_update_dpp(NINF, __float_as_int(v), 0x143, 0xc, 0xf, false)));
  return v;
}
// block reductions (prologue only)
__device__ __forceinline__ float block_sum8(float v, float* red8, int tid){
  __syncthreads();
  v = dpp_wave_sum(v);
  if ((tid & 63) == 63) red8[tid >> 6] = v;
  __syncthreads();
  float o = red8[0];
  #pragma unroll
  for (int w = 1; w < 8; ++w) o += red8[w];
  return o;
}
__device__ __forceinline__ float block_max8(float v, float* red8, int tid){
  __syncthreads();
  v = dpp_wave_max(v);
  if ((tid & 63) == 63) red8[tid >> 6] = v;
  __syncthreads();
  float o = red8[0];
  #pragma unroll
  for (int w = 1; w < 8; ++w) o = fmaxf(o, red8[w]);
  return o;
}

__device__ __forceinline__ unsigned pack_bf16(float a, float b){
  unsigned bx = __float_as_uint(a); bx = (bx + 0x7fffu + ((bx >> 16) & 1u)) >> 16;
  unsigned by = __float_as_uint(b); by = (by + 0x7fffu + ((by >> 16) & 1u)) >> 16;
  return bx | (by << 16);
}

// hybrid half-row matvec: 25 packed dwords from VGPRs + 25 from LDS slab
__device__ __forceinline__ float mv_hybrid(const unsigned* mreg,
                                           const unsigned* __restrict__ slab,
                                           const float* __restrict__ vv,
                                           int tid, int half){
  const float2* v2 = (const float2*)vv + half * 50;
  const unsigned* sl = slab + tid * SLAB_STRIDE;
  float a0=0.f, a1=0.f, a2=0.f, a3=0.f;
  #pragma unroll
  for (int k = 0; k < 25; ++k){
    unsigned u = mreg[k]; float2 x = v2[k];
    a0 = fmaf(__uint_as_float(u << 16),          x.x, a0);
    a1 = fmaf(__uint_as_float(u & 0xffff0000u),  x.y, a1);
  }
  #pragma unroll
  for (int k = 0; k < 25; ++k){
    unsigned u = sl[k]; float2 x = v2[25 + k];
    a2 = fmaf(__uint_as_float(u << 16),          x.x, a2);
    a3 = fmaf(__uint_as_float(u & 0xffff0000u),  x.y, a3);
  }
  return (a0 + a1) + (a2 + a3);
}

extern "C" __global__ __launch_bounds__(NTHREADS)   // NOTE: no 2nd arg — any
// waves-per-EU hint makes the allocator clamp to 64 VGPRs and spill mreg
// (R4/R6 evidence: WRITE_SIZE 33.7MB / 3.05GB). Plain form allocates ~100.
void rb_kernel(const float* __restrict__ x,  const float* __restrict__ Sigma,
               const float* __restrict__ W1, const float* __restrict__ b1,
               const float* __restrict__ W2, const float* __restrict__ b2,
               float* __restrict__ out) {
  __shared__ __align__(16) unsigned slab[400 * SLAB_STRIDE];   // 43.2 KB
  __shared__ __align__(16) float yv[NA];
  __shared__ __align__(16) float pv[NA];
  __shared__ __align__(16) float partial[NA];
  __shared__ __align__(16) float bcv[NA];
  __shared__ float xs[NF];
  __shared__ float hs[H_DIM];
  __shared__ float redA[8], redB[8], redC[8], redD[8], red8[8];

  const int tid  = threadIdx.x;
  const int s    = blockIdx.x;
  const bool act = tid < 400;
  const int row  = tid >> 1;              // valid when act
  const int half = tid & 1;
  const bool owner = act && (half == 0);
  const float* S = Sigma + (size_t)s * NA * NA;

  if (tid < NF) xs[tid] = x[s * NF + tid];
  float sd = 0.f;
  if (owner) sd = S[(size_t)row * NA + row];

  // ---- stage Sigma directly: 25 packed dwords -> VGPRs, 25 -> private slab row ----
  // Only the owning thread ever reads its slab row -> no staging barriers.
  unsigned mreg[25];
  if (act){
    const float2* rowp = (const float2*)S + (size_t)row * 100 + half * 50;
    #pragma unroll
    for (int k = 0; k < 25; ++k){
      float2 w = rowp[k];
      mreg[k] = pack_bf16(w.x, w.y);
    }
    unsigned* sl = slab + tid * SLAB_STRIDE;
    #pragma unroll
    for (int k = 0; k < 25; ++k){
      float2 w = rowp[25 + k];
      sl[k] = pack_bf16(w.x, w.y);
    }
  }

  // ---- MLP ----
  __syncthreads();                        // xs visible
  if (tid < H_DIM){
    const float* w = W1 + tid * NF;
    float acc = b1[tid];
    #pragma unroll 8
    for (int j = 0; j < NF; ++j) acc += w[j] * xs[j];
    hs[tid] = (acc >= 0.f) ? acc : ALPHA_LR * acc;
  }
  __syncthreads();
  float logit = -INFINITY;
  if (tid < NA){
    const float* w = W2 + tid * H_DIM;
    float acc = b2[tid];
    #pragma unroll 8
    for (int j = 0; j < H_DIM; ++j) acc += w[j] * hs[j];
    logit = acc;
  }

  // ---- softmax -> b (output 2); clamp+renorm -> bcv ----
  float mx = block_max8(logit, red8, tid);
  float e  = (tid < NA) ? expf(logit - mx) : 0.f;
  float es = block_sum8(e, red8, tid);
  float bsoft = e / es;
  if (tid < NA) out[(size_t)B_SAMPLES * NA + (size_t)s * NA + tid] = bsoft;
  float bcl = fmaxf(bsoft, B_MIN_C);
  float bs  = block_sum8((tid < NA) ? bcl : 0.f, red8, tid);
  if (tid < NA) bcv[tid] = bcl / bs;
  __syncthreads();                               // bcv visible

  float b_ = owner ? bcv[row] : 0.f;
  float y  = 0.f;
  if (owner) yv[row] = b_;

  // ---- y0 = bc / sqrt(bc^T S bc) ----
  __syncthreads();                               // yv visible
  {
    float acc = act ? mv_hybrid(mreg, slab, yv, tid, half) : 0.f;
    float q   = acc + __shfl_xor(acc, 1, 64);
    float wq  = dpp_wave_sum(owner ? b_ * q : 0.f);
    if ((tid & 63) == 63) redA[tid >> 6] = wq;
    __syncthreads();
    float quad = redA[0]+redA[1]+redA[2]+redA[3]+redA[4]+redA[5]+redA[6]+redA[7];
    if (owner){ y = b_ / sqrtf(quad); yv[row] = y; }
  }

  // ---- damped inexact Newton ----
  float gg0 = 1.f;
  bool  ph1done = false;
  int   nexact  = 0;
  for (int it = 0; it < N_PH1 + N_REFINE; ++it){
    if (nexact >= N_REFINE) break;
    const bool exact = ph1done;
    if (exact) ++nexact;

    // --- gradient matvec q = (S y)_row ---
    float q = 0.f;
    if (exact){
      __syncthreads();                           // yv visible, partial free
      int lane = tid & 63, wid = tid >> 6;
      int r0 = wid * ROWS_PER_WAVE;
      for (int rr = r0; rr < r0 + ROWS_PER_WAVE; ++rr){
        const float* rowp = S + (size_t)rr * NA;
        float a = rowp[lane]*yv[lane] + rowp[lane+64]*yv[lane+64]
                + rowp[lane+128]*yv[lane+128];
        if (lane < NA - 192) a += rowp[lane+192]*yv[lane+192];
        a = dpp_wave_sum(a);
        if (lane == 63) partial[rr] = a;
      }
      __syncthreads();
      if (owner) q = partial[row];
    } else {
      __syncthreads();                           // yv visible
      float acc = act ? mv_hybrid(mreg, slab, yv, tid, half) : 0.f;
      q = acc + __shfl_xor(acc, 1, 64);
    }

    // --- Newton init ---
    float g=0.f, d=0.f, mi=0.f, r=0.f, z=0.f, dy=0.f, pj=0.f;
    if (owner){
      g  = q - b_ / y;
      d  = b_ / (y * y);
      mi = 1.f / (sd + d);
      r  = -g; z = mi * r; pj = z;
      pv[row] = z;
    }
    float wg = dpp_wave_sum(owner ? g * g : 0.f);
    float wz = dpp_wave_sum(owner ? r * z : 0.f);
    if ((tid & 63) == 63){ redA[tid >> 6] = wg; redB[tid >> 6] = wz; }
    __syncthreads();
    float gg = redA[0]+redA[1]+redA[2]+redA[3]+redA[4]+redA[5]+redA[6]+redA[7];
    float rz = redB[0]+redB[1]+redB[2]+redB[3]+redB[4]+redB[5]+redB[6]+redB[7];
    if (it == 0) gg0 = fmaxf(gg, 1e-30f);
    float tol2 = exact ? TOL2_LO
                       : fminf(TOL2_HI, fmaxf(TOL2_LO, 4.f * (gg / gg0)));

    if (gg > 1e-24f){
      // --- Jacobi-PCG, fused single reduction (pq, rq, qq) ---
      const float rz0 = rz;
      for (int j = 0; j < CG_MAX; ++j){
        __syncthreads();                         // B1: pv visible, red reuse safe
        float acc = act ? mv_hybrid(mreg, slab, pv, tid, half) : 0.f;
        float qp  = acc + __shfl_xor(acc, 1, 64);
        float qf=0.f, cpq=0.f, crq=0.f, cqq=0.f;
        if (owner){
          qf = qp + d * pj;
          float u = mi * qf;
          cpq = pj * qf; crq = r * u; cqq = qf * u;
        }
        cpq = dpp_wave_sum(cpq); crq = dpp_wave_sum(crq); cqq = dpp_wave_sum(cqq);
        if ((tid & 63) == 63){ redA[tid>>6]=cpq; redB[tid>>6]=crq; redC[tid>>6]=cqq; }
        __syncthreads();                         // B2
        float pq = redA[0]+redA[1]+redA[2]+redA[3]+redA[4]+redA[5]+redA[6]+redA[7];
        float rq = redB[0]+redB[1]+redB[2]+redB[3]+redB[4]+redB[5]+redB[6]+redB[7];
        float qq = redC[0]+redC[1]+redC[2]+redC[3]+redC[4]+redC[5]+redC[6]+redC[7];
        float alpha = rz / pq;
        float rznew = fmaxf(fmaf(alpha*alpha, qq, fmaf(-2.f*alpha, rq, rz)), 0.f);
        if (owner){
          dy = fmaf(alpha, pj, dy);
          r  = fmaf(-alpha, qf, r);
          z  = mi * r;
        }
        bool brk = (rznew <= tol2 * rz0) || (j == CG_MAX - 1);
        if (!brk){
          float beta = rznew / rz;
          if (owner){ pj = fmaf(beta, pj, z); pv[row] = pj; }
        }
        rz = rznew;
        if (brk) break;
      }

      // --- damped step keeping y > 0 (reference semantics) ---
      float ratio = (owner && dy < 0.f) ? (-y / dy) : 1e30f;
      float wmn = dpp_wave_min(ratio);
      if ((tid & 63) == 63) redD[tid >> 6] = wmn;
      __syncthreads();
      float mr = fminf(fminf(fminf(redD[0],redD[1]),fminf(redD[2],redD[3])),
                       fminf(fminf(redD[4],redD[5]),fminf(redD[6],redD[7])));
      float t = fminf(1.f, 0.9f * mr);
      if (owner){ y = fmaxf(fmaf(t, dy, y), 1e-12f); yv[row] = y; }
    }

    if (!exact && (gg <= 1e-8f * gg0 || it + 1 >= N_PH1)) ph1done = true;
  }

  // ---- z = y / sum(y) (output 1) ----
  float wy = dpp_wave_sum(owner ? y : 0.f);
  if ((tid & 63) == 63) redA[tid >> 6] = wy;   // safe: barrier passed since last redA read
  __syncthreads();
  float ys = redA[0]+redA[1]+redA[2]+redA[3]+redA[4]+redA[5]+redA[6]+redA[7];
  if (owner) out[(size_t)s * NA + row] = y / ys;
}

extern "C" void kernel_launch(void* const* d_in, const int* in_sizes, int n_in,
                              void* d_out, int out_size, void* d_ws, size_t ws_size,
                              hipStream_t stream) {
  const float* x     = (const float*)d_in[0];
  const float* Sigma = (const float*)d_in[1];
  const float* W1    = (const float*)d_in[2];
  const float* b1    = (const float*)d_in[3];
  const float* W2    = (const float*)d_in[4];
  const float* b2    = (const float*)d_in[5];
  float* out = (float*)d_out;
  hipLaunchKernelGGL(rb_kernel, dim3(B_SAMPLES), dim3(NTHREADS), 0, stream,
                     x, Sigma, W1, b1, W2, b2, out);
}

// Round 9
// 458.286 us; speedup vs baseline: 2.6976x; 1.1307x over previous
//
#include <hip/hip_runtime.h>
#include <math.h>

#define NF        128
#define H_DIM     256
#define NA        200
#define B_SAMPLES 512
#define ALPHA_LR  0.01f
#define B_MIN_C   1e-4f

#define NTHREADS  512
#define ROWS_PER_WAVE 25            // exact-path: 8 waves x 25 rows
#define SLAB_STRIDE 27              // 26 used + 1 pad; odd -> 2-way bank aliasing (free)

#define N_PH1     10
#define N_REFINE  2
#define CG_MAX    40
#define TOL2_LO   4e-4f             // refinement CG tolerance
#define TOL2_P1   1e-3f             // phase-1 CG tolerance floor
#define TOL2_HI   2.5e-2f

typedef _Float16 h2_t __attribute__((ext_vector_type(2)));

__device__ __forceinline__ h2_t as_h2(unsigned u){
  union { unsigned u; h2_t h; } c; c.u = u; return c.h;
}
__device__ __forceinline__ unsigned pk_f16(float a, float b){
#if __has_builtin(__builtin_amdgcn_cvt_pkrtz)
  // builtin returns __fp16 ext_vector(2); bit-cast via union (no implicit conv)
  union { decltype(__builtin_amdgcn_cvt_pkrtz(0.f, 0.f)) h; unsigned u; } c;
  c.h = __builtin_amdgcn_cvt_pkrtz(a, b);
  return c.u;
#else
  union { h2_t h; unsigned u; } c;
  c.h = (h2_t){ (_Float16)a, (_Float16)b };
  return c.u;
#endif
}
__device__ __forceinline__ float fdot2(unsigned m, unsigned v, float acc){
#if __has_builtin(__builtin_amdgcn_fdot2)
  return __builtin_amdgcn_fdot2(as_h2(m), as_h2(v), acc, false);
#else
  h2_t a = as_h2(m), b = as_h2(v);
  return fmaf((float)a.y, (float)b.y, fmaf((float)a.x, (float)b.x, acc));
#endif
}

// ---------------- DPP wave-64 reductions (result valid in lane 63) --------
__device__ __forceinline__ float dpp_wave_sum(float v){
  v += __int_as_float(__builtin_amdgcn_update_dpp(0, __float_as_int(v), 0x111, 0xf, 0xf, false));
  v += __int_as_float(__builtin_amdgcn_update_dpp(0, __float_as_int(v), 0x112, 0xf, 0xf, false));
  v += __int_as_float(__builtin_amdgcn_update_dpp(0, __float_as_int(v), 0x114, 0xf, 0xf, false));
  v += __int_as_float(__builtin_amdgcn_update_dpp(0, __float_as_int(v), 0x118, 0xf, 0xf, false));
  v += __int_as_float(__builtin_amdgcn_update_dpp(0, __float_as_int(v), 0x142, 0xa, 0xf, false));
  v += __int_as_float(__builtin_amdgcn_update_dpp(0, __float_as_int(v), 0x143, 0xc, 0xf, false));
  return v;
}
__device__ __forceinline__ float dpp_wave_min(float v){
  const int PINF = 0x7f800000;
  v = fminf(v, __int_as_float(__builtin_amdgcn_update_dpp(PINF, __float_as_int(v), 0x111, 0xf, 0xf, false)));
  v = fminf(v, __int_as_float(__builtin_amdgcn_update_dpp(PINF, __float_as_int(v), 0x112, 0xf, 0xf, false)));
  v = fminf(v, __int_as_float(__builtin_amdgcn_update_dpp(PINF, __float_as_int(v), 0x114, 0xf, 0xf, false)));
  v = fminf(v, __int_as_float(__builtin_amdgcn_update_dpp(PINF, __float_as_int(v), 0x118, 0xf, 0xf, false)));
  v = fminf(v, __int_as_float(__builtin_amdgcn_update_dpp(PINF, __float_as_int(v), 0x142, 0xa, 0xf, false)));
  v = fminf(v, __int_as_float(__builtin_amdgcn_update_dpp(PINF, __float_as_int(v), 0x143, 0xc, 0xf, false)));
  return v;
}
__device__ __forceinline__ float dpp_wave_max(float v){
  const int NINF = 0xff800000;
  v = fmaxf(v, __int_as_float(__builtin_amdgcn_update_dpp(NINF, __float_as_int(v), 0x111, 0xf, 0xf, false)));
  v = fmaxf(v, __int_as_float(__builtin_amdgcn_update_dpp(NINF, __float_as_int(v), 0x112, 0xf, 0xf, false)));
  v = fmaxf(v, __int_as_float(__builtin_amdgcn_update_dpp(NINF, __float_as_int(v), 0x114, 0xf, 0xf, false)));
  v = fmaxf(v, __int_as_float(__builtin_amdgcn_update_dpp(NINF, __float_as_int(v), 0x118, 0xf, 0xf, false)));
  v = fmaxf(v, __int_as_float(__builtin_amdgcn_update_dpp(NINF, __float_as_int(v), 0x142, 0xa, 0xf, false)));
  v = fmaxf(v, __int_as_float(__builtin_amdgcn_update_dpp(NINF, __float_as_int(v), 0x143, 0xc, 0xf, false)));
  return v;
}
// block reductions (prologue only)
__device__ __forceinline__ float block_sum8(float v, float* red8, int tid){
  __syncthreads();
  v = dpp_wave_sum(v);
  if ((tid & 63) == 63) red8[tid >> 6] = v;
  __syncthreads();
  float o = red8[0];
  #pragma unroll
  for (int w = 1; w < 8; ++w) o += red8[w];
  return o;
}
__device__ __forceinline__ float block_max8(float v, float* red8, int tid){
  __syncthreads();
  v = dpp_wave_max(v);
  if ((tid & 63) == 63) red8[tid >> 6] = v;
  __syncthreads();
  float o = red8[0];
  #pragma unroll
  for (int w = 1; w < 8; ++w) o = fmaxf(o, red8[w]);
  return o;
}

// packed-f16 half-row matvec via v_dot2_f32_f16: 24 dwords VGPR + 26 LDS slab
__device__ __forceinline__ float mv_dot2(const unsigned* mreg,
                                         const unsigned* __restrict__ sl,
                                         const unsigned* __restrict__ vh,
                                         int half){
  const unsigned* v = vh + half * 50;
  float a0=0.f, a1=0.f, a2=0.f, a3=0.f;
  #pragma unroll
  for (int k = 0; k < 12; ++k){
    a0 = fdot2(mreg[2*k],   v[2*k],   a0);
    a1 = fdot2(mreg[2*k+1], v[2*k+1], a1);
  }
  #pragma unroll
  for (int k = 0; k < 13; ++k){
    a2 = fdot2(sl[2*k],   v[24+2*k],   a2);
    a3 = fdot2(sl[2*k+1], v[24+2*k+1], a3);
  }
  return (a0 + a1) + (a2 + a3);
}

// f16-matrix x fp32-vector half-row matvec (phase-1 gradient; avoids f16
// rounding of y so the Newton fixed point stays exactly solvable)
__device__ __forceinline__ float mv_f32v(const unsigned* mreg,
                                         const unsigned* __restrict__ sl,
                                         const float* __restrict__ vv,
                                         int half){
  const float2* v2 = (const float2*)vv + half * 50;
  float a0=0.f, a1=0.f, a2=0.f, a3=0.f;
  #pragma unroll
  for (int p = 0; p < 24; ++p){
    h2_t h = as_h2(mreg[p]); float2 x = v2[p];
    a0 = fmaf((float)h.x, x.x, a0);
    a1 = fmaf((float)h.y, x.y, a1);
  }
  #pragma unroll
  for (int p = 0; p < 26; ++p){
    h2_t h = as_h2(sl[p]); float2 x = v2[24 + p];
    a2 = fmaf((float)h.x, x.x, a2);
    a3 = fmaf((float)h.y, x.y, a3);
  }
  return (a0 + a1) + (a2 + a3);
}

extern "C" __global__ __launch_bounds__(NTHREADS)   // NOTE: no 2nd arg — any
// waves-per-EU hint clamps the allocator to 64 VGPRs and spills mreg
// (R4/R6 evidence: WRITE_SIZE 33.7MB / 3.05GB). Plain form allocates ~100+.
void rb_kernel(const float* __restrict__ x,  const float* __restrict__ Sigma,
               const float* __restrict__ W1, const float* __restrict__ b1,
               const float* __restrict__ W2, const float* __restrict__ b2,
               float* __restrict__ out) {
  __shared__ __align__(16) unsigned slab[400 * SLAB_STRIDE];   // 43.2 KB
  __shared__ __align__(16) unsigned ph[100];   // packed-f16 CG vector (and b at init)
  __shared__ __align__(16) float yv[NA];
  __shared__ __align__(16) float partial[NA];
  __shared__ __align__(16) float bcv[NA];
  __shared__ float xs[NF];
  __shared__ float hs[H_DIM];
  __shared__ float redA[8], redB[8], redC[8], redD[8], red8[8];

  const int tid  = threadIdx.x;
  const int s    = blockIdx.x;
  const bool act = tid < 400;
  const int row  = tid >> 1;              // valid when act
  const int half = tid & 1;
  const bool owner = act && (half == 0);
  const float* S = Sigma + (size_t)s * NA * NA;

  if (tid < NF) xs[tid] = x[s * NF + tid];
  float sd = 0.f;
  if (owner) sd = S[(size_t)row * NA + row];

  // ---- stage Sigma: packed f16; 24 dwords -> VGPRs, 26 -> private slab row ----
  // Only the owning thread reads its slab row -> no staging barriers.
  unsigned mreg[24];
  unsigned* slmine = slab + tid * SLAB_STRIDE;
  if (act){
    const float4* rowp = (const float4*)S + (size_t)row * 50 + half * 25;
    #pragma unroll
    for (int k = 0; k < 12; ++k){
      float4 w = rowp[k];
      mreg[2*k]   = pk_f16(w.x, w.y);
      mreg[2*k+1] = pk_f16(w.z, w.w);
    }
    #pragma unroll
    for (int k = 0; k < 13; ++k){
      float4 w = rowp[12 + k];
      slmine[2*k]   = pk_f16(w.x, w.y);
      slmine[2*k+1] = pk_f16(w.z, w.w);
    }
  }

  // ---- MLP ----
  __syncthreads();                        // xs visible
  if (tid < H_DIM){
    const float* w = W1 + tid * NF;
    float acc = b1[tid];
    #pragma unroll 8
    for (int j = 0; j < NF; ++j) acc += w[j] * xs[j];
    hs[tid] = (acc >= 0.f) ? acc : ALPHA_LR * acc;
  }
  __syncthreads();
  float logit = -INFINITY;
  if (tid < NA){
    const float* w = W2 + tid * H_DIM;
    float acc = b2[tid];
    #pragma unroll 8
    for (int j = 0; j < H_DIM; ++j) acc += w[j] * hs[j];
    logit = acc;
  }

  // ---- softmax -> b (output 2); clamp+renorm -> bcv ----
  float mx = block_max8(logit, red8, tid);
  float e  = (tid < NA) ? expf(logit - mx) : 0.f;
  float es = block_sum8(e, red8, tid);
  float bsoft = e / es;
  if (tid < NA) out[(size_t)B_SAMPLES * NA + (size_t)s * NA + tid] = bsoft;
  float bcl = fmaxf(bsoft, B_MIN_C);
  float bs  = block_sum8((tid < NA) ? bcl : 0.f, red8, tid);
  if (tid < NA) bcv[tid] = bcl / bs;
  __syncthreads();                               // bcv visible

  float b_ = owner ? bcv[row] : 0.f;
  float y  = 0.f;
  if (owner) ((unsigned short*)ph)[row] = (unsigned short)(pk_f16(b_, 0.f) & 0xffffu);

  // ---- y0 = bc / sqrt(bc^T S bc) ----
  __syncthreads();                               // ph visible
  {
    float acc = act ? mv_dot2(mreg, slmine, ph, half) : 0.f;
    float q   = acc + __shfl_xor(acc, 1, 64);
    float wq  = dpp_wave_sum(owner ? b_ * q : 0.f);
    if ((tid & 63) == 63) redA[tid >> 6] = wq;
    __syncthreads();
    float quad = redA[0]+redA[1]+redA[2]+redA[3]+redA[4]+redA[5]+redA[6]+redA[7];
    if (owner){ y = b_ / sqrtf(quad); yv[row] = y; }
  }

  // ---- damped inexact Newton ----
  float gg0 = 1.f;
  bool  ph1done = false;
  int   nexact  = 0;
  for (int it = 0; it < N_PH1 + N_REFINE; ++it){
    if (nexact >= N_REFINE) break;
    const bool exact = ph1done;
    if (exact) ++nexact;

    // --- gradient matvec q = (S y)_row (fp32 y, f16 or exact matrix) ---
    float q = 0.f;
    if (exact){
      __syncthreads();                           // yv visible, partial free
      int lane = tid & 63, wid = tid >> 6;
      int r0 = wid * ROWS_PER_WAVE;
      for (int rr = r0; rr < r0 + ROWS_PER_WAVE; ++rr){
        const float* rowp = S + (size_t)rr * NA;
        float a = rowp[lane]*yv[lane] + rowp[lane+64]*yv[lane+64]
                + rowp[lane+128]*yv[lane+128];
        if (lane < NA - 192) a += rowp[lane+192]*yv[lane+192];
        a = dpp_wave_sum(a);
        if (lane == 63) partial[rr] = a;
      }
      __syncthreads();
      if (owner) q = partial[row];
    } else {
      __syncthreads();                           // yv visible
      float acc = act ? mv_f32v(mreg, slmine, yv, half) : 0.f;
      q = acc + __shfl_xor(acc, 1, 64);
    }

    // --- Newton init; reduce gg and rz together ---
    float g=0.f, d=0.f, mi=0.f;
    if (owner){
      g  = q - b_ / y;
      d  = b_ / (y * y);
      mi = 1.f / (sd + d);
    }
    float wg = dpp_wave_sum(owner ? g * g : 0.f);
    float wz = dpp_wave_sum(owner ? g * g * mi : 0.f);   // rz = g^T M^-1 g
    if ((tid & 63) == 63){ redA[tid >> 6] = wg; redB[tid >> 6] = wz; }
    __syncthreads();
    float gg = redA[0]+redA[1]+redA[2]+redA[3]+redA[4]+redA[5]+redA[6]+redA[7];
    float rz = redB[0]+redB[1]+redB[2]+redB[3]+redB[4]+redB[5]+redB[6]+redB[7];
    if (it == 0) gg0 = fmaxf(gg, 1e-30f);
    float tol2 = exact ? TOL2_LO
                       : fminf(TOL2_HI, fmaxf(TOL2_P1, 4.f * (gg / gg0)));

    if (gg > 1e-24f){
      // --- scale CG system by 1/||g|| so packed-f16 p never underflows ---
      const float cinv = rsqrtf(gg);
      const float csc  = sqrtf(gg);
      float r=0.f, z=0.f, dy=0.f, pj=0.f;
      if (owner){
        r  = -g * cinv;
        z  = mi * r;
        pj = z;
        ((unsigned short*)ph)[row] = (unsigned short)(pk_f16(pj, 0.f) & 0xffffu);
      }
      rz = rz * cinv * cinv;

      // --- Jacobi-PCG, fused single reduction (pq, rq, qq) ---
      const float rz0 = rz;
      for (int j = 0; j < CG_MAX; ++j){
        __syncthreads();                         // B1: ph visible, red reuse safe
        float acc = act ? mv_dot2(mreg, slmine, ph, half) : 0.f;
        float qp  = acc + __shfl_xor(acc, 1, 64);
        float qf=0.f, cpq=0.f, crq=0.f, cqq=0.f;
        if (owner){
          qf = qp + d * pj;
          float u = mi * qf;
          cpq = pj * qf; crq = r * u; cqq = qf * u;
        }
        cpq = dpp_wave_sum(cpq); crq = dpp_wave_sum(crq); cqq = dpp_wave_sum(cqq);
        if ((tid & 63) == 63){ redA[tid>>6]=cpq; redB[tid>>6]=crq; redC[tid>>6]=cqq; }
        __syncthreads();                         // B2
        float pq = redA[0]+redA[1]+redA[2]+redA[3]+redA[4]+redA[5]+redA[6]+redA[7];
        float rq = redB[0]+redB[1]+redB[2]+redB[3]+redB[4]+redB[5]+redB[6]+redB[7];
        float qq = redC[0]+redC[1]+redC[2]+redC[3]+redC[4]+redC[5]+redC[6]+redC[7];
        float alpha = rz / pq;
        float rznew = fmaxf(fmaf(alpha*alpha, qq, fmaf(-2.f*alpha, rq, rz)), 0.f);
        if (owner){
          dy = fmaf(alpha, pj, dy);
          r  = fmaf(-alpha, qf, r);
          z  = mi * r;
        }
        bool brk = (rznew <= tol2 * rz0) || (j == CG_MAX - 1);
        if (!brk){
          float beta = rznew / rz;
          if (owner){
            pj = fmaf(beta, pj, z);
            ((unsigned short*)ph)[row] = (unsigned short)(pk_f16(pj, 0.f) & 0xffffu);
          }
        }
        rz = rznew;
        if (brk) break;
      }

      // --- unscale dy; damped step keeping y > 0 (reference semantics) ---
      if (owner) dy *= csc;
      float ratio = (owner && dy < 0.f) ? (-y / dy) : 1e30f;
      float wmn = dpp_wave_min(ratio);
      if ((tid & 63) == 63) redD[tid >> 6] = wmn;
      __syncthreads();
      float mr = fminf(fminf(fminf(redD[0],redD[1]),fminf(redD[2],redD[3])),
                       fminf(fminf(redD[4],redD[5]),fminf(redD[6],redD[7])));
      float t = fminf(1.f, 0.9f * mr);
      if (owner){ y = fmaxf(fmaf(t, dy, y), 1e-12f); yv[row] = y; }
    }

    if (!exact && (gg <= 1e-8f * gg0 || it + 1 >= N_PH1)) ph1done = true;
  }

  // ---- z = y / sum(y) (output 1) ----
  float wy = dpp_wave_sum(owner ? y : 0.f);
  if ((tid & 63) == 63) redA[tid >> 6] = wy;   // safe: barrier passed since last redA read
  __syncthreads();
  float ys = redA[0]+redA[1]+redA[2]+redA[3]+redA[4]+redA[5]+redA[6]+redA[7];
  if (owner) out[(size_t)s * NA + row] = y / ys;
}

extern "C" void kernel_launch(void* const* d_in, const int* in_sizes, int n_in,
                              void* d_out, int out_size, void* d_ws, size_t ws_size,
                              hipStream_t stream) {
  const float* x     = (const float*)d_in[0];
  const float* Sigma = (const float*)d_in[1];
  const float* W1    = (const float*)d_in[2];
  const float* b1    = (const float*)d_in[3];
  const float* W2    = (const float*)d_in[4];
  const float* b2    = (const float*)d_in[5];
  float* out = (float*)d_out;
  hipLaunchKernelGGL(rb_kernel, dim3(B_SAMPLES), dim3(NTHREADS), 0, stream,
                     x, Sigma, W1, b1, W2, b2, out);
}

// Round 10
// 367.691 us; speedup vs baseline: 3.3623x; 1.2464x over previous
//
#include <hip/hip_runtime.h>
#include <math.h>

#define NF        128
#define H_DIM     256
#define NA        200
#define B_SAMPLES 512
#define ALPHA_LR  0.01f
#define B_MIN_C   1e-4f

#define NTHREADS  512
#define ROWS_PER_WAVE 25            // exact-path: 8 waves x 25 rows

#define N_PH1     10
#define N_REFINE  1
#define CG_MAX    40
#define TOL2_LO   4e-4f             // refinement CG tolerance
#define TOL2_P1   1e-3f             // phase-1 CG tolerance floor
#define TOL2_HI   2.5e-2f

typedef _Float16 h2_t __attribute__((ext_vector_type(2)));
typedef unsigned uv4  __attribute__((ext_vector_type(4)));

__device__ __forceinline__ h2_t as_h2(unsigned u){
  union { unsigned u; h2_t h; } c; c.u = u; return c.h;
}
__device__ __forceinline__ unsigned pk_f16(float a, float b){
#if __has_builtin(__builtin_amdgcn_cvt_pkrtz)
  union { decltype(__builtin_amdgcn_cvt_pkrtz(0.f, 0.f)) h; unsigned u; } c;
  c.h = __builtin_amdgcn_cvt_pkrtz(a, b);
  return c.u;
#else
  union { h2_t h; unsigned u; } c;
  c.h = (h2_t){ (_Float16)a, (_Float16)b };
  return c.u;
#endif
}
__device__ __forceinline__ float fdot2(unsigned m, unsigned v, float acc){
#if __has_builtin(__builtin_amdgcn_fdot2)
  return __builtin_amdgcn_fdot2(as_h2(m), as_h2(v), acc, false);
#else
  h2_t a = as_h2(m), b = as_h2(v);
  return fmaf((float)a.y, (float)b.y, fmaf((float)a.x, (float)b.x, acc));
#endif
}

// ---------------- DPP wave-64 reductions (result valid in lane 63) --------
__device__ __forceinline__ float dpp_wave_sum(float v){
  v += __int_as_float(__builtin_amdgcn_update_dpp(0, __float_as_int(v), 0x111, 0xf, 0xf, false));
  v += __int_as_float(__builtin_amdgcn_update_dpp(0, __float_as_int(v), 0x112, 0xf, 0xf, false));
  v += __int_as_float(__builtin_amdgcn_update_dpp(0, __float_as_int(v), 0x114, 0xf, 0xf, false));
  v += __int_as_float(__builtin_amdgcn_update_dpp(0, __float_as_int(v), 0x118, 0xf, 0xf, false));
  v += __int_as_float(__builtin_amdgcn_update_dpp(0, __float_as_int(v), 0x142, 0xa, 0xf, false));
  v += __int_as_float(__builtin_amdgcn_update_dpp(0, __float_as_int(v), 0x143, 0xc, 0xf, false));
  return v;
}
__device__ __forceinline__ float dpp_wave_min(float v){
  const int PINF = 0x7f800000;
  v = fminf(v, __int_as_float(__builtin_amdgcn_update_dpp(PINF, __float_as_int(v), 0x111, 0xf, 0xf, false)));
  v = fminf(v, __int_as_float(__builtin_amdgcn_update_dpp(PINF, __float_as_int(v), 0x112, 0xf, 0xf, false)));
  v = fminf(v, __int_as_float(__builtin_amdgcn_update_dpp(PINF, __float_as_int(v), 0x114, 0xf, 0xf, false)));
  v = fminf(v, __int_as_float(__builtin_amdgcn_update_dpp(PINF, __float_as_int(v), 0x118, 0xf, 0xf, false)));
  v = fminf(v, __int_as_float(__builtin_amdgcn_update_dpp(PINF, __float_as_int(v), 0x142, 0xa, 0xf, false)));
  v = fminf(v, __int_as_float(__builtin_amdgcn_update_dpp(PINF, __float_as_int(v), 0x143, 0xc, 0xf, false)));
  return v;
}
__device__ __forceinline__ float dpp_wave_max(float v){
  const int NINF = 0xff800000;
  v = fmaxf(v, __int_as_float(__builtin_amdgcn_update_dpp(NINF, __float_as_int(v), 0x111, 0xf, 0xf, false)));
  v = fmaxf(v, __int_as_float(__builtin_amdgcn_update_dpp(NINF, __float_as_int(v), 0x112, 0xf, 0xf, false)));
  v = fmaxf(v, __int_as_float(__builtin_amdgcn_update_dpp(NINF, __float_as_int(v), 0x114, 0xf, 0xf, false)));
  v = fmaxf(v, __int_as_float(__builtin_amdgcn_update_dpp(NINF, __float_as_int(v), 0x118, 0xf, 0xf, false)));
  v = fmaxf(v, __int_as_float(__builtin_amdgcn_update_dpp(NINF, __float_as_int(v), 0x142, 0xa, 0xf, false)));
  v = fmaxf(v, __int_as_float(__builtin_amdgcn_update_dpp(NINF, __float_as_int(v), 0x143, 0xc, 0xf, false)));
  return v;
}
// block reductions (prologue only)
__device__ __forceinline__ float block_sum8(float v, float* red8, int tid){
  __syncthreads();
  v = dpp_wave_sum(v);
  if ((tid & 63) == 63) red8[tid >> 6] = v;
  __syncthreads();
  float o = red8[0];
  #pragma unroll
  for (int w = 1; w < 8; ++w) o += red8[w];
  return o;
}
__device__ __forceinline__ float block_max8(float v, float* red8, int tid){
  __syncthreads();
  v = dpp_wave_max(v);
  if ((tid & 63) == 63) red8[tid >> 6] = v;
  __syncthreads();
  float o = red8[0];
  #pragma unroll
  for (int w = 1; w < 8; ++w) o = fmaxf(o, red8[w]);
  return o;
}

// owner writes its f16 vector entry; halves padded to 56 dwords (16B aligned)
__device__ __forceinline__ void put_ph(unsigned short* phs, int row, float v){
  unsigned short h = (unsigned short)(pk_f16(v, 0.f) & 0xffffu);
  phs[(row < 100) ? row : (row + 12)] = h;     // rows>=100 live at shorts 112+
}

// packed-f16 matvec via v_dot2_f32_f16; v: 13 b128 reads, slab: 7 b128 reads
__device__ __forceinline__ float mv_dot2(const unsigned* mreg,
                                         const uv4* __restrict__ sl4,
                                         const unsigned* __restrict__ ph,
                                         int half){
  const uv4* v4 = (const uv4*)(ph + half * 56);
  float a0=0.f, a1=0.f, a2=0.f, a3=0.f;
  #pragma unroll
  for (int k = 0; k < 6; ++k){
    uv4 vv = v4[k];
    a0 = fdot2(mreg[4*k+0], vv.x, a0);
    a1 = fdot2(mreg[4*k+1], vv.y, a1);
    a2 = fdot2(mreg[4*k+2], vv.z, a2);
    a3 = fdot2(mreg[4*k+3], vv.w, a3);
  }
  #pragma unroll
  for (int k = 0; k < 6; ++k){
    uv4 vv = v4[6 + k];
    uv4 mm = sl4[k * 400];
    a0 = fdot2(mm.x, vv.x, a0);
    a1 = fdot2(mm.y, vv.y, a1);
    a2 = fdot2(mm.z, vv.z, a2);
    a3 = fdot2(mm.w, vv.w, a3);
  }
  { uv4 vv = v4[12]; uv4 mm = sl4[6 * 400];
    a0 = fdot2(mm.x, vv.x, a0); a1 = fdot2(mm.y, vv.y, a1); }
  return (a0 + a1) + (a2 + a3);
}

// f16-matrix x fp32-vector (phase-1 gradient: exact fixed point of f16 system)
__device__ __forceinline__ float mv_f32v(const unsigned* mreg,
                                         const uv4* __restrict__ sl4,
                                         const float* __restrict__ vv,
                                         int half){
  const float4* v4 = (const float4*)(vv + half * 100);
  float a0=0.f, a1=0.f;
  #pragma unroll
  for (int k = 0; k < 6; ++k){
    float4 va = v4[2*k], vb = v4[2*k+1];
    h2_t m0 = as_h2(mreg[4*k+0]), m1 = as_h2(mreg[4*k+1]);
    h2_t m2 = as_h2(mreg[4*k+2]), m3 = as_h2(mreg[4*k+3]);
    a0 = fmaf((float)m0.x, va.x, a0); a1 = fmaf((float)m0.y, va.y, a1);
    a0 = fmaf((float)m1.x, va.z, a0); a1 = fmaf((float)m1.y, va.w, a1);
    a0 = fmaf((float)m2.x, vb.x, a0); a1 = fmaf((float)m2.y, vb.y, a1);
    a0 = fmaf((float)m3.x, vb.z, a0); a1 = fmaf((float)m3.y, vb.w, a1);
  }
  #pragma unroll
  for (int k = 0; k < 6; ++k){
    float4 va = v4[12 + 2*k], vb = v4[13 + 2*k];
    uv4 mm = sl4[k * 400];
    h2_t m0 = as_h2(mm.x), m1 = as_h2(mm.y), m2 = as_h2(mm.z), m3 = as_h2(mm.w);
    a0 = fmaf((float)m0.x, va.x, a0); a1 = fmaf((float)m0.y, va.y, a1);
    a0 = fmaf((float)m1.x, va.z, a0); a1 = fmaf((float)m1.y, va.w, a1);
    a0 = fmaf((float)m2.x, vb.x, a0); a1 = fmaf((float)m2.y, vb.y, a1);
    a0 = fmaf((float)m3.x, vb.z, a0); a1 = fmaf((float)m3.y, vb.w, a1);
  }
  { float4 va = v4[24]; uv4 mm = sl4[6 * 400];
    h2_t m0 = as_h2(mm.x), m1 = as_h2(mm.y);
    a0 = fmaf((float)m0.x, va.x, a0); a1 = fmaf((float)m0.y, va.y, a1);
    a0 = fmaf((float)m1.x, va.z, a0); a1 = fmaf((float)m1.y, va.w, a1); }
  return a0 + a1;
}

extern "C" __global__ __launch_bounds__(NTHREADS)   // NOTE: no 2nd arg — any
// waves-per-EU hint clamps the allocator to 64 VGPRs and spills mreg
// (R4/R6 evidence: WRITE_SIZE 33.7MB / 3.05GB). Plain form allocates ~100+.
void rb_kernel(const float* __restrict__ x,  const float* __restrict__ Sigma,
               const float* __restrict__ W1, const float* __restrict__ b1,
               const float* __restrict__ W2, const float* __restrict__ b2,
               float* __restrict__ out) {
  __shared__ __align__(16) uv4 slab4[7 * 400];        // 44.8 KB, k-major
  __shared__ __align__(16) unsigned ph[112];          // packed f16 vec, 56/half
  __shared__ __align__(16) float yv[NA];
  __shared__ __align__(16) float partial[NA];
  __shared__ __align__(16) float bcv[NA];
  __shared__ float xs[NF];
  __shared__ float hs[H_DIM];
  __shared__ float redA[8], redB[8], redC[8], redD[8], red8[8];

  const int tid  = threadIdx.x;
  const int s    = blockIdx.x;
  const bool act = tid < 400;
  const int row  = tid >> 1;              // valid when act
  const int half = tid & 1;
  const bool owner = act && (half == 0);
  const float* S = Sigma + (size_t)s * NA * NA;
  unsigned short* phs = (unsigned short*)ph;

  if (tid < NF) xs[tid] = x[s * NF + tid];
  float sd = 0.f;
  if (owner) sd = S[(size_t)row * NA + row];

  // ---- stage Sigma (packed f16): 24 dwords -> VGPRs, 28 -> k-major slab ----
  // Only the owning thread reads its slab entries -> no staging barriers.
  unsigned mreg[24];
  const uv4* sl4 = slab4 + tid;
  if (act){
    const float4* rowp = (const float4*)S + (size_t)row * 50 + half * 25;
    #pragma unroll
    for (int k = 0; k < 6; ++k){
      float4 wa = rowp[2*k], wb = rowp[2*k+1];
      mreg[4*k+0] = pk_f16(wa.x, wa.y);
      mreg[4*k+1] = pk_f16(wa.z, wa.w);
      mreg[4*k+2] = pk_f16(wb.x, wb.y);
      mreg[4*k+3] = pk_f16(wb.z, wb.w);
    }
    #pragma unroll
    for (int k = 0; k < 6; ++k){
      float4 wa = rowp[12 + 2*k], wb = rowp[13 + 2*k];
      uv4 u;
      u.x = pk_f16(wa.x, wa.y); u.y = pk_f16(wa.z, wa.w);
      u.z = pk_f16(wb.x, wb.y); u.w = pk_f16(wb.z, wb.w);
      slab4[k * 400 + tid] = u;
    }
    { float4 wa = rowp[24];
      uv4 u; u.x = pk_f16(wa.x, wa.y); u.y = pk_f16(wa.z, wa.w); u.z = 0u; u.w = 0u;
      slab4[6 * 400 + tid] = u; }
  }

  // ---- MLP ----
  __syncthreads();                        // xs visible
  if (tid < H_DIM){
    const float* w = W1 + tid * NF;
    float acc = b1[tid];
    #pragma unroll 8
    for (int j = 0; j < NF; ++j) acc += w[j] * xs[j];
    hs[tid] = (acc >= 0.f) ? acc : ALPHA_LR * acc;
  }
  __syncthreads();
  float logit = -INFINITY;
  if (tid < NA){
    const float* w = W2 + tid * H_DIM;
    float acc = b2[tid];
    #pragma unroll 8
    for (int j = 0; j < H_DIM; ++j) acc += w[j] * hs[j];
    logit = acc;
  }

  // ---- softmax -> b (output 2); clamp+renorm -> bcv ----
  float mx = block_max8(logit, red8, tid);
  float e  = (tid < NA) ? expf(logit - mx) : 0.f;
  float es = block_sum8(e, red8, tid);
  float bsoft = e / es;
  if (tid < NA) out[(size_t)B_SAMPLES * NA + (size_t)s * NA + tid] = bsoft;
  float bcl = fmaxf(bsoft, B_MIN_C);
  float bs  = block_sum8((tid < NA) ? bcl : 0.f, red8, tid);
  if (tid < NA) bcv[tid] = bcl / bs;
  __syncthreads();                               // bcv visible

  float b_ = owner ? bcv[row] : 0.f;
  float y  = 0.f;
  if (owner) put_ph(phs, row, b_);

  // ---- y0 = bc / sqrt(bc^T S bc) ----
  __syncthreads();                               // ph visible
  {
    float acc = act ? mv_dot2(mreg, sl4, ph, half) : 0.f;
    float q   = acc + __shfl_xor(acc, 1, 64);
    float wq  = dpp_wave_sum(owner ? b_ * q : 0.f);
    if ((tid & 63) == 63) redA[tid >> 6] = wq;
    __syncthreads();
    float quad = redA[0]+redA[1]+redA[2]+redA[3]+redA[4]+redA[5]+redA[6]+redA[7];
    if (owner){ y = b_ / sqrtf(quad); yv[row] = y; }
  }

  // ---- damped inexact Newton ----
  float gg0 = 1.f;
  bool  ph1done = false;
  int   nexact  = 0;
  for (int it = 0; it < N_PH1 + N_REFINE; ++it){
    if (nexact >= N_REFINE) break;
    const bool exact = ph1done;
    if (exact) ++nexact;

    // --- gradient matvec q = (S y)_row (fp32 y, f16 or exact matrix) ---
    float q = 0.f;
    if (exact){
      __syncthreads();                           // yv visible, partial free
      int lane = tid & 63, wid = tid >> 6;
      int r0 = wid * ROWS_PER_WAVE;
      for (int rr = r0; rr < r0 + ROWS_PER_WAVE; ++rr){
        const float* rowp = S + (size_t)rr * NA;
        float a = rowp[lane]*yv[lane] + rowp[lane+64]*yv[lane+64]
                + rowp[lane+128]*yv[lane+128];
        if (lane < NA - 192) a += rowp[lane+192]*yv[lane+192];
        a = dpp_wave_sum(a);
        if (lane == 63) partial[rr] = a;
      }
      __syncthreads();
      if (owner) q = partial[row];
    } else {
      __syncthreads();                           // yv visible
      float acc = act ? mv_f32v(mreg, sl4, yv, half) : 0.f;
      q = acc + __shfl_xor(acc, 1, 64);
    }

    // --- Newton init; reduce gg and rz together ---
    float g=0.f, d=0.f, mi=0.f;
    if (owner){
      g  = q - b_ / y;
      d  = b_ / (y * y);
      mi = 1.f / (sd + d);
    }
    float wg = dpp_wave_sum(owner ? g * g : 0.f);
    float wz = dpp_wave_sum(owner ? g * g * mi : 0.f);   // rz = g^T M^-1 g
    if ((tid & 63) == 63){ redA[tid >> 6] = wg; redB[tid >> 6] = wz; }
    __syncthreads();
    float gg = redA[0]+redA[1]+redA[2]+redA[3]+redA[4]+redA[5]+redA[6]+redA[7];
    float rz = redB[0]+redB[1]+redB[2]+redB[3]+redB[4]+redB[5]+redB[6]+redB[7];
    if (it == 0) gg0 = fmaxf(gg, 1e-30f);
    float tol2 = exact ? TOL2_LO
                       : fminf(TOL2_HI, fmaxf(TOL2_P1, 4.f * (gg / gg0)));

    if (gg > 1e-24f){
      // --- scale CG system by 1/||g|| so packed-f16 p never underflows ---
      const float cinv = rsqrtf(gg);
      const float csc  = sqrtf(gg);
      float r=0.f, z=0.f, dy=0.f, pj=0.f;
      if (owner){
        r  = -g * cinv;
        z  = mi * r;
        pj = z;
        put_ph(phs, row, pj);
      }
      rz = rz * cinv * cinv;

      // --- Jacobi-PCG, fused single reduction (pq, rq, qq) ---
      const float rz0 = rz;
      for (int j = 0; j < CG_MAX; ++j){
        __syncthreads();                         // B1: ph visible, red reuse safe
        float acc = act ? mv_dot2(mreg, sl4, ph, half) : 0.f;
        float qp  = acc + __shfl_xor(acc, 1, 64);
        float qf=0.f, cpq=0.f, crq=0.f, cqq=0.f;
        if (owner){
          qf = qp + d * pj;
          float u = mi * qf;
          cpq = pj * qf; crq = r * u; cqq = qf * u;
        }
        cpq = dpp_wave_sum(cpq); crq = dpp_wave_sum(crq); cqq = dpp_wave_sum(cqq);
        if ((tid & 63) == 63){ redA[tid>>6]=cpq; redB[tid>>6]=crq; redC[tid>>6]=cqq; }
        __syncthreads();                         // B2
        float pq = redA[0]+redA[1]+redA[2]+redA[3]+redA[4]+redA[5]+redA[6]+redA[7];
        float rq = redB[0]+redB[1]+redB[2]+redB[3]+redB[4]+redB[5]+redB[6]+redB[7];
        float qq = redC[0]+redC[1]+redC[2]+redC[3]+redC[4]+redC[5]+redC[6]+redC[7];
        float alpha = rz / pq;
        float rznew = fmaxf(fmaf(alpha*alpha, qq, fmaf(-2.f*alpha, rq, rz)), 0.f);
        if (owner){
          dy = fmaf(alpha, pj, dy);
          r  = fmaf(-alpha, qf, r);
          z  = mi * r;
        }
        bool brk = (rznew <= tol2 * rz0) || (j == CG_MAX - 1);
        if (!brk){
          float beta = rznew / rz;
          if (owner){ pj = fmaf(beta, pj, z); put_ph(phs, row, pj); }
        }
        rz = rznew;
        if (brk) break;
      }

      // --- unscale dy; damped step keeping y > 0 (reference semantics) ---
      if (owner) dy *= csc;
      float ratio = (owner && dy < 0.f) ? (-y / dy) : 1e30f;
      float wmn = dpp_wave_min(ratio);
      if ((tid & 63) == 63) redD[tid >> 6] = wmn;
      __syncthreads();
      float mr = fminf(fminf(fminf(redD[0],redD[1]),fminf(redD[2],redD[3])),
                       fminf(fminf(redD[4],redD[5]),fminf(redD[6],redD[7])));
      float t = fminf(1.f, 0.9f * mr);
      if (owner){
        y = fmaxf(fmaf(t, dy, y), 1e-12f);
        yv[row] = y;
        put_ph(phs, row, y);                     // repack y for next f16 use
      }
    }

    if (!exact && (gg <= 1e-8f * gg0 || it + 1 >= N_PH1)) ph1done = true;
  }

  // ---- z = y / sum(y) (output 1) ----
  float wy = dpp_wave_sum(owner ? y : 0.f);
  if ((tid & 63) == 63) redA[tid >> 6] = wy;   // safe: barrier passed since last redA read
  __syncthreads();
  float ys = redA[0]+redA[1]+redA[2]+redA[3]+redA[4]+redA[5]+redA[6]+redA[7];
  if (owner) out[(size_t)s * NA + row] = y / ys;
}

extern "C" void kernel_launch(void* const* d_in, const int* in_sizes, int n_in,
                              void* d_out, int out_size, void* d_ws, size_t ws_size,
                              hipStream_t stream) {
  const float* x     = (const float*)d_in[0];
  const float* Sigma = (const float*)d_in[1];
  const float* W1    = (const float*)d_in[2];
  const float* b1    = (const float*)d_in[3];
  const float* W2    = (const float*)d_in[4];
  const float* b2    = (const float*)d_in[5];
  float* out = (float*)d_out;
  hipLaunchKernelGGL(rb_kernel, dim3(B_SAMPLES), dim3(NTHREADS), 0, stream,
                     x, Sigma, W1, b1, W2, b2, out);
}